// Round 1
// baseline (262.828 us; speedup 1.0000x reference)
//
#include <hip/hip_runtime.h>

#define NJ 55

// SMPL-X parent table (compile-time constant so unrolled indexing folds).
__device__ constexpr int kPar[NJ] = {
    -1, 0, 0, 0, 1, 2, 3, 4, 5, 6, 7, 8, 9, 9, 9, 12, 13, 14, 16, 17,
    18, 19, 15, 22, 23, 20, 25, 26, 20, 28, 29, 20, 31, 32, 20, 34, 35,
    20, 37, 38, 21, 40, 41, 21, 43, 44, 21, 46, 47, 21, 49, 50, 21, 52, 53
};

// One thread per (b,t) sample. Fully unrolled topological walk over the
// 55-joint tree; live world-rotation set in topo order is <= ~4 matrices,
// so everything stays in registers after SROA.
__global__ __launch_bounds__(256)
void fk_kernel(const float* __restrict__ motion,  // [BT, 55, 3, 3]
               const float* __restrict__ Jrest,   // [55, 3]
               float* __restrict__ out,           // [BT, 55, 3]
               int BT)
{
    __shared__ float rel[NJ * 3];

    // Precompute relative joint offsets once per block (J is tiny; L2-hot).
    if (threadIdx.x < NJ) {
        const int j = threadIdx.x;
        const int p = kPar[j];
        float x = Jrest[j * 3 + 0];
        float y = Jrest[j * 3 + 1];
        float z = Jrest[j * 3 + 2];
        if (p >= 0) {
            x -= Jrest[p * 3 + 0];
            y -= Jrest[p * 3 + 1];
            z -= Jrest[p * 3 + 2];
        }
        rel[j * 3 + 0] = x;
        rel[j * 3 + 1] = y;
        rel[j * 3 + 2] = z;
    }
    __syncthreads();

    const int g = blockIdx.x * blockDim.x + threadIdx.x;
    if (g >= BT) return;

    const float* __restrict__ m = motion + (size_t)g * (NJ * 9);
    float* __restrict__ o = out + (size_t)g * (NJ * 3);

    // World transforms per joint. All indices are compile-time constants
    // after full unroll -> promoted to registers, dead entries eliminated.
    float R[NJ][9];
    float t[NJ][3];

#pragma unroll
    for (int j = 0; j < NJ; ++j) {
        const float b0 = m[j * 9 + 0];
        const float b1 = m[j * 9 + 1];
        const float b2 = m[j * 9 + 2];
        const float b3 = m[j * 9 + 3];
        const float b4 = m[j * 9 + 4];
        const float b5 = m[j * 9 + 5];
        const float b6 = m[j * 9 + 6];
        const float b7 = m[j * 9 + 7];
        const float b8 = m[j * 9 + 8];

        const float rx = rel[j * 3 + 0];
        const float ry = rel[j * 3 + 1];
        const float rz = rel[j * 3 + 2];

        const int p = kPar[j];
        if (p < 0) {
            R[j][0] = b0; R[j][1] = b1; R[j][2] = b2;
            R[j][3] = b3; R[j][4] = b4; R[j][5] = b5;
            R[j][6] = b6; R[j][7] = b7; R[j][8] = b8;
            t[j][0] = rx;
            t[j][1] = ry;
            t[j][2] = rz;
        } else {
            const float a0 = R[p][0], a1 = R[p][1], a2 = R[p][2];
            const float a3 = R[p][3], a4 = R[p][4], a5 = R[p][5];
            const float a6 = R[p][6], a7 = R[p][7], a8 = R[p][8];

            // C = A @ B
            R[j][0] = a0 * b0 + a1 * b3 + a2 * b6;
            R[j][1] = a0 * b1 + a1 * b4 + a2 * b7;
            R[j][2] = a0 * b2 + a1 * b5 + a2 * b8;
            R[j][3] = a3 * b0 + a4 * b3 + a5 * b6;
            R[j][4] = a3 * b1 + a4 * b4 + a5 * b7;
            R[j][5] = a3 * b2 + a4 * b5 + a5 * b8;
            R[j][6] = a6 * b0 + a7 * b3 + a8 * b6;
            R[j][7] = a6 * b1 + a7 * b4 + a8 * b7;
            R[j][8] = a6 * b2 + a7 * b5 + a8 * b8;

            // t = A @ rel + t_parent
            t[j][0] = a0 * rx + a1 * ry + a2 * rz + t[p][0];
            t[j][1] = a3 * rx + a4 * ry + a5 * rz + t[p][1];
            t[j][2] = a6 * rx + a7 * ry + a8 * rz + t[p][2];
        }

        o[j * 3 + 0] = t[j][0];
        o[j * 3 + 1] = t[j][1];
        o[j * 3 + 2] = t[j][2];
    }
}

extern "C" void kernel_launch(void* const* d_in, const int* in_sizes, int n_in,
                              void* d_out, int out_size, void* d_ws, size_t ws_size,
                              hipStream_t stream) {
    const float* motion = (const float*)d_in[0];
    const float* Jrest  = (const float*)d_in[1];
    float* out = (float*)d_out;

    const int BT = in_sizes[0] / (NJ * 9);  // 32 * 2048 = 65536

    const int block = 256;
    const int grid = (BT + block - 1) / block;
    fk_kernel<<<grid, block, 0, stream>>>(motion, Jrest, out, BT);
}

// Round 4
// 235.438 us; speedup vs baseline: 1.1163x; 1.1163x over previous
//
#include <hip/hip_runtime.h>
#include <stdint.h>

#define NJ   55
#define JT   5                 // joints per tile
#define NT   11                // tiles (55 = 11*5)
#define SPB  64                // samples per block == block size (1 wave)
#define TFL  (JT * 9)          // 45 floats per sample per tile
#define OFL  (JT * 3)          // 15 out floats per sample per tile

// SMPL-X parent table (compile-time constant; indices fold after unroll).
__device__ constexpr int kPar[NJ] = {
    -1, 0, 0, 0, 1, 2, 3, 4, 5, 6, 7, 8, 9, 9, 9, 12, 13, 14, 16, 17,
    18, 19, 15, 22, 23, 20, 25, 26, 20, 28, 29, 20, 31, 32, 20, 34, 35,
    20, 37, 38, 21, 40, 41, 21, 43, 44, 21, 46, 47, 21, 49, 50, 21, 52, 53
};

typedef const __attribute__((address_space(1))) void glb_v;
typedef __attribute__((address_space(3))) void lds_v;

// One wave per block; 64 samples per block; joint-tiles double-buffered in
// LDS via async global_load_lds DMA with counted vmcnt (prefetch stays in
// flight across compute). Outputs staged in LDS, flushed coalesced.
__global__ __launch_bounds__(64)
void fk_kernel(const float* __restrict__ motion,  // [BT, 55, 9]
               const float* __restrict__ Jrest,   // [55, 3]
               float* __restrict__ out,           // [BT, 55, 3]
               int BT)
{
    __shared__ float lds_in[2][SPB * TFL];   // 2 x 11520 B
    __shared__ float lds_out[SPB * OFL];     // 3840 B
    __shared__ float lds_rel[NJ * 3];        // 660 B

    const int lane  = threadIdx.x;           // 0..63
    const int blk_s = blockIdx.x * SPB;      // first sample of this block

    // Relative rest-pose offsets (tiny; one-time).
    if (lane < NJ) {
        const int p = kPar[lane];
        float x = Jrest[lane * 3 + 0];
        float y = Jrest[lane * 3 + 1];
        float z = Jrest[lane * 3 + 2];
        if (p >= 0) {
            x -= Jrest[p * 3 + 0];
            y -= Jrest[p * 3 + 1];
            z -= Jrest[p * 3 + 2];
        }
        lds_rel[lane * 3 + 0] = x;
        lds_rel[lane * 3 + 1] = y;
        lds_rel[lane * 3 + 2] = z;
    }
    __syncthreads();   // before any DMA is outstanding; safe to drain here

    const float* __restrict__ mbase = motion + (size_t)blk_s * (NJ * 9);

    // Stage tile T's 64x45 floats into lds_in[BUF] via async DMA.
    // LDS dest is wave-uniform base + lane*4 (linear); per-lane global addr
    // implements the [sample][float] gather. idx = it*64+lane == s*45+e.
#define STAGE(T, BUF)                                                        \
    do {                                                                     \
        _Pragma("unroll")                                                    \
        for (int it = 0; it < TFL; ++it) {                                   \
            const int idx = it * SPB + lane;                                 \
            const int s   = idx / TFL;          /* magic-mul div by 45 */    \
            const int e   = idx - s * TFL;                                   \
            const float* gp = mbase + (size_t)s * (NJ * 9) + (T) * TFL + e;  \
            __builtin_amdgcn_global_load_lds(                                \
                (glb_v*)gp, (lds_v*)&lds_in[BUF][it * SPB], 4, 0, 0);        \
        }                                                                    \
    } while (0)

    // World transforms; all indices compile-time after full unroll -> SROA.
    float Rw[NJ][9];
    float tw[NJ][3];

    STAGE(0, 0);   // prolog

#pragma unroll
    for (int t = 0; t < NT; ++t) {
        if (t < NT - 1) {
            STAGE(t + 1, (t + 1) & 1);
            // Wait for all but the newest 45 VMEM ops: tile t's DMAs and any
            // older flush stores complete; tile t+1's 45 DMAs stay in flight.
            asm volatile("s_waitcnt vmcnt(45)" ::: "memory");
        } else {
            asm volatile("s_waitcnt vmcnt(0)" ::: "memory");
        }
        __builtin_amdgcn_sched_barrier(0);

        const float* __restrict__ Lin = &lds_in[t & 1][0];

#pragma unroll
        for (int q = 0; q < JT; ++q) {
            const int j = t * JT + q;

            const float b0 = Lin[lane * TFL + q * 9 + 0];
            const float b1 = Lin[lane * TFL + q * 9 + 1];
            const float b2 = Lin[lane * TFL + q * 9 + 2];
            const float b3 = Lin[lane * TFL + q * 9 + 3];
            const float b4 = Lin[lane * TFL + q * 9 + 4];
            const float b5 = Lin[lane * TFL + q * 9 + 5];
            const float b6 = Lin[lane * TFL + q * 9 + 6];
            const float b7 = Lin[lane * TFL + q * 9 + 7];
            const float b8 = Lin[lane * TFL + q * 9 + 8];

            const float rx = lds_rel[j * 3 + 0];   // uniform addr: broadcast
            const float ry = lds_rel[j * 3 + 1];
            const float rz = lds_rel[j * 3 + 2];

            const int p = kPar[j];
            if (p < 0) {
                Rw[j][0] = b0; Rw[j][1] = b1; Rw[j][2] = b2;
                Rw[j][3] = b3; Rw[j][4] = b4; Rw[j][5] = b5;
                Rw[j][6] = b6; Rw[j][7] = b7; Rw[j][8] = b8;
                tw[j][0] = rx; tw[j][1] = ry; tw[j][2] = rz;
            } else {
                const float a0 = Rw[p][0], a1 = Rw[p][1], a2 = Rw[p][2];
                const float a3 = Rw[p][3], a4 = Rw[p][4], a5 = Rw[p][5];
                const float a6 = Rw[p][6], a7 = Rw[p][7], a8 = Rw[p][8];

                Rw[j][0] = a0 * b0 + a1 * b3 + a2 * b6;
                Rw[j][1] = a0 * b1 + a1 * b4 + a2 * b7;
                Rw[j][2] = a0 * b2 + a1 * b5 + a2 * b8;
                Rw[j][3] = a3 * b0 + a4 * b3 + a5 * b6;
                Rw[j][4] = a3 * b1 + a4 * b4 + a5 * b7;
                Rw[j][5] = a3 * b2 + a4 * b5 + a5 * b8;
                Rw[j][6] = a6 * b0 + a7 * b3 + a8 * b6;
                Rw[j][7] = a6 * b1 + a7 * b4 + a8 * b7;
                Rw[j][8] = a6 * b2 + a7 * b5 + a8 * b8;

                tw[j][0] = a0 * rx + a1 * ry + a2 * rz + tw[p][0];
                tw[j][1] = a3 * rx + a4 * ry + a5 * rz + tw[p][1];
                tw[j][2] = a6 * rx + a7 * ry + a8 * rz + tw[p][2];
            }

            lds_out[lane * OFL + q * 3 + 0] = tw[j][0];
            lds_out[lane * OFL + q * 3 + 1] = tw[j][1];
            lds_out[lane * OFL + q * 3 + 2] = tw[j][2];
        }

        // Coalesced flush of this tile's outputs (within-wave LDS ordering
        // is in-order on CDNA; no barrier -> prefetch DMAs stay in flight).
#pragma unroll
        for (int it = 0; it < OFL; ++it) {
            const int idx = it * SPB + lane;
            const int s   = idx / OFL;          // magic-mul div by 15
            const int e   = idx - s * OFL;
            out[(size_t)(blk_s + s) * (NJ * 3) + t * OFL + e] = lds_out[idx];
        }
    }
#undef STAGE
}

extern "C" void kernel_launch(void* const* d_in, const int* in_sizes, int n_in,
                              void* d_out, int out_size, void* d_ws, size_t ws_size,
                              hipStream_t stream) {
    const float* motion = (const float*)d_in[0];
    const float* Jrest  = (const float*)d_in[1];
    float* out = (float*)d_out;

    const int BT = in_sizes[0] / (NJ * 9);   // 65536

    const int grid = (BT + SPB - 1) / SPB;   // 1024 blocks of 64
    fk_kernel<<<grid, SPB, 0, stream>>>(motion, Jrest, out, BT);
}